// Round 7
// baseline (322.255 us; speedup 1.0000x reference)
//
#include <hip/hip_runtime.h>

#define BATCH   1024
#define IDIM    256
#define ODIM    256
#define GRIDSZ  300
#define KS_     64             // K-splits over i
#define IPW     4              // i per block = IDIM/KS_
#define CHUNKS  19             // g-chunks of 16 pairs per i (last chunk: 4 pad slots)
#define NSTEPS  (IPW * CHUNKS) // 76
#define INV2PI  0.15915494309189535f

typedef __attribute__((ext_vector_type(8))) short  short8;
typedef __attribute__((ext_vector_type(4))) float  f32x4;
typedef __attribute__((ext_vector_type(4))) unsigned int u32x4;

// bf16 pair pack: round-half-up + v_perm byte select (3 VALU ops). PROVEN.
// low16 = bf16(c), high16 = bf16(s).
__device__ __forceinline__ unsigned pk(float c, float s) {
  unsigned a = __float_as_uint(c) + 0x8000u;
  unsigned b = __float_as_uint(s) + 0x8000u;
  return __builtin_amdgcn_perm(b, a, 0x07060302u);
}

// async global->LDS DMA, 16B per lane (lane-linear dest). [m97/m03, R5-proven]
__device__ __forceinline__ void dma16(const float* g, const float* l) {
  __builtin_amdgcn_global_load_lds(
      (const __attribute__((address_space(1))) unsigned int*)(g),
      (__attribute__((address_space(3))) unsigned int*)(l), 16, 0, 0);
}

// (c,s) *= (C,S)  — Givens rotation, 2 mul + 2 fma
__device__ __forceinline__ void rot(float& c, float& s, float C, float S) {
  float t1 = s * S, t2 = c * S;
  float cn = __builtin_fmaf(c, C, -t1);
  s = __builtin_fmaf(s, C, t2);
  c = cn;
}

// cos/sin of 2*pi*rev via v_fract + v_cos (revolutions; exact range reduction)
__device__ __forceinline__ void cossin(float rev, float& c, float& s) {
  c = __builtin_amdgcn_cosf(__builtin_amdgcn_fractf(rev));
  s = __builtin_amdgcn_cosf(__builtin_amdgcn_fractf(rev - 0.25f));
}

__global__ void init_out(const float* __restrict__ bias, float* __restrict__ out) {
  const int idx = blockIdx.x * 256 + threadIdx.x;
  out[idx] = bias[idx & (ODIM - 1)];
}

// R6 (2-deep DMA pipeline, counted vmcnt, raw barriers) + convoy breaking:
//  (a) one-time s_sleep phase-stagger at entry: co-resident blocks start one
//      chunk-period apart, so their post-barrier LDS/DMA bursts interleave
//      instead of colliding (R6 PMC: no pipe >52% busy, 48% idle -> queueing
//      stall from phase-aligned bursts, not latency).
//  (b) s_setprio(1) around the MFMA+A-gen cluster (T5): with de-phased
//      blocks, compute-phase waves win issue arbitration over staging-phase
//      waves (role diversity now exists across blocks).
// Sync structure, addressing, pad handling byte-identical to R6 (passing).
__global__ __launch_bounds__(256, 4) void fkan_pipe(
    const float* __restrict__ x, const float* __restrict__ fc,
    float* __restrict__ out) {
  __shared__ alignas(16) unsigned int Bp[2][1024];   // packed bf16-pair dbuf, 8 KB
  __shared__ alignas(16) float Bf[2][2048];          // fp32 DMA landing, 16 KB

  const int tid = threadIdx.x, id = blockIdx.x;
  // XCD swizzle: the 4 m-siblings of one (n,ks) are consecutive on XCD id&7.
  const int z = id & 7;
  const int m = (id >> 3) & 3;           // M/256
  const int nk = (id >> 5) * 8 + z;      // 0..255
  const int n  = nk & 3;                 // N/64
  const int ks = nk >> 2;                // 0..63

  // convoy breaker: stagger co-resident blocks by ~1 chunk period (1300 cyc).
  // slot hash covers both consecutive-per-CU and stride-8 co-residency.
  {
    const int slot = ((id >> 3) ^ (id >> 8)) & 3;
    for (int t = 0; t < slot; ++t) __builtin_amdgcn_s_sleep(20);  // 20*64 cyc
  }

  const int wave = tid >> 6, lane = tid & 63;
  const int fr = lane & 15, fq = lane >> 4;
  const int mbase = m * 256 + wave * 64;   // 4 waves stacked along M
  const int nbase = n * 64;

  f32x4 acc[4][4];
#pragma unroll
  for (int a_ = 0; a_ < 4; ++a_)
#pragma unroll
    for (int b_ = 0; b_ < 4; ++b_)
      acc[a_][b_] = (f32x4){0.f, 0.f, 0.f, 0.f};

  float r1c[4], r1s[4], r16c[4], r16s[4], sc_[4], ss_[4];

  const float* b1 = fc + (size_t)ODIM * IDIM * GRIDSZ;   // sin-coef plane

  // staging thread's fc offset: row j = nbase+wave*16+fr, i = ks*IPW+il,
  // g = gchunk*16 + fq*4
  int fo = ((nbase + wave * 16 + fr) * IDIM + ks * IPW) * GRIDSZ + fq * 4;
  const int sa = wave * 256 + lane * 4;     // lane-linear slot (dwords)

  // prologue: DMA chunks 0 (parity 0) and 1 (parity 1)
  dma16(fc + fo, &Bf[0][sa]);
  dma16(b1 + fo, &Bf[0][1024 + sa]);
  fo += 16;                                 // chunk 1 (no wrap, no pad)
  dma16(fc + fo, &Bf[1][sa]);
  dma16(b1 + fo, &Bf[1][1024 + sa]);

  // pack chunk 0 -> Bp[0]; chunk 1's 2 DMAs stay in flight
  asm volatile("s_waitcnt vmcnt(2)" ::: "memory");
  {
    const f32x4 La = *(const f32x4*)&Bf[0][sa];
    const f32x4 Lb = *(const f32x4*)&Bf[0][1024 + sa];
    *(u32x4*)&Bp[0][sa] =
        (u32x4){pk(La.x, Lb.x), pk(La.y, Lb.y), pk(La.z, Lb.z), pk(La.w, Lb.w)};
  }

  int gs = 0, il = 0;      // compute-chunk counters (chunk S)
  int gd = 2;              // g-index of next DMA chunk (S+2)
  bool zpA = false;        // pad flag for the chunk packed this iter (S+1)

#pragma unroll 2
  for (int S = 0; S < NSTEPS; ++S) {
    __builtin_amdgcn_sched_barrier(0);
    asm volatile("s_waitcnt lgkmcnt(0)" ::: "memory");  // Bp writes committed
    __builtin_amdgcn_s_barrier();                       // NO vmcnt drain
    __builtin_amdgcn_sched_barrier(0);

    // seed A recurrence at i-boundaries (S = 0,19,38,57) BEFORE DMA issue,
    // so the compiler's wait for x doesn't drain the DMA queue.
    if (gs == 0) {
      const int i = ks * IPW + il;
#pragma unroll
      for (int tI = 0; tI < 4; ++tI) {
        const float xr = x[(size_t)(mbase + tI * 16 + fr) * IDIM + i] * INV2PI;
        cossin(xr, r1c[tI], r1s[tI]);                   // delta-k = 1
        cossin(16.0f * xr, r16c[tI], r16s[tI]);         // delta-g = 16 per chunk
        cossin((float)(fq * 4 + 1) * xr, sc_[tI], ss_[tI]);
      }
    }

    // issue DMA for chunk S+2 into Bf[S&1] (parity const under unroll-2)
    bool zpB = false;
    if (S < NSTEPS - 2) {
      if (gd == 0) fo += GRIDSZ - (CHUNKS - 1) * 16;   // row wrap: +12
      else fo += 16;
      zpB = (gd == CHUNKS - 1) & (fq == 3);            // pad quads of S+2
      const int sub = zpB ? 4 : 0;                     // shift in-bounds
      dma16(fc + fo - sub, &Bf[S & 1][sa]);
      dma16(b1 + fo - sub, &Bf[S & 1][1024 + sa]);
      gd++; if (gd == CHUNKS) gd = 0;
    }

    // B fragments for this chunk (all 4 waves read all 4 frags)
    const unsigned int* buf = &Bp[S & 1][0];
    short8 bV0 = __builtin_bit_cast(short8, *(const u32x4*)(buf + lane * 4));
    short8 bV1 = __builtin_bit_cast(short8, *(const u32x4*)(buf + 256 + lane * 4));
    short8 bV2 = __builtin_bit_cast(short8, *(const u32x4*)(buf + 512 + lane * 4));
    short8 bV3 = __builtin_bit_cast(short8, *(const u32x4*)(buf + 768 + lane * 4));

    // A frags on the fly + MFMA (pad k-slots hit zeroed B dwords).
    // setprio: favor compute-phase waves over staging-phase waves (T5).
    __builtin_amdgcn_s_setprio(1);
#pragma unroll
    for (int tI = 0; tI < 4; ++tI) {
      float c = sc_[tI], s = ss_[tI];
      unsigned a0 = pk(c, s);
      rot(c, s, r1c[tI], r1s[tI]); unsigned a1 = pk(c, s);
      rot(c, s, r1c[tI], r1s[tI]); unsigned a2 = pk(c, s);
      rot(c, s, r1c[tI], r1s[tI]); unsigned a3 = pk(c, s);
      rot(sc_[tI], ss_[tI], r16c[tI], r16s[tI]);   // advance state by delta-g=16
      short8 aV = __builtin_bit_cast(short8, (u32x4){a0, a1, a2, a3});
      acc[tI][0] = __builtin_amdgcn_mfma_f32_16x16x32_bf16(aV, bV0, acc[tI][0], 0, 0, 0);
      acc[tI][1] = __builtin_amdgcn_mfma_f32_16x16x32_bf16(aV, bV1, acc[tI][1], 0, 0, 0);
      acc[tI][2] = __builtin_amdgcn_mfma_f32_16x16x32_bf16(aV, bV2, acc[tI][2], 0, 0, 0);
      acc[tI][3] = __builtin_amdgcn_mfma_f32_16x16x32_bf16(aV, bV3, acc[tI][3], 0, 0, 0);
    }
    __builtin_amdgcn_s_setprio(0);

    // pack chunk S+1: counted vmcnt leaves chunk S+2's DMAs in flight
    if (S < NSTEPS - 1) {
      if (S < NSTEPS - 2) {
        asm volatile("s_waitcnt vmcnt(2)" ::: "memory");
      } else {
        asm volatile("s_waitcnt vmcnt(0)" ::: "memory");  // last chunk: drain
      }
      const f32x4 La = *(const f32x4*)&Bf[(S + 1) & 1][sa];
      const f32x4 Lb = *(const f32x4*)&Bf[(S + 1) & 1][1024 + sa];
      u32x4 w = (u32x4){pk(La.x, Lb.x), pk(La.y, Lb.y),
                        pk(La.z, Lb.z), pk(La.w, Lb.w)};
      if (zpA) w = (u32x4){0u, 0u, 0u, 0u};
      *(u32x4*)&Bp[(S + 1) & 1][sa] = w;
    }
    zpA = zpB;
    gs++; if (gs == CHUNKS) { gs = 0; ++il; }
  }

  // epilogue: C/D layout col=lane&15, row=(lane>>4)*4+reg [m89]; K-split fp32 atomics
  const int ob = mbase + fq * 4;
  const int oj = nbase + fr;
#pragma unroll
  for (int tI = 0; tI < 4; ++tI)
#pragma unroll
    for (int tJ = 0; tJ < 4; ++tJ) {
      float* dst = out + (size_t)(ob + tI * 16) * ODIM + (oj + tJ * 16);
#pragma unroll
      for (int rr = 0; rr < 4; ++rr)
        unsafeAtomicAdd(dst + rr * ODIM, acc[tI][tJ][rr]);
    }
}

extern "C" void kernel_launch(void* const* d_in, const int* in_sizes, int n_in,
                              void* d_out, int out_size, void* d_ws, size_t ws_size,
                              hipStream_t stream) {
  const float* x    = (const float*)d_in[0];
  const float* fc   = (const float*)d_in[1];
  const float* bias = (const float*)d_in[2];
  float* out = (float*)d_out;

  init_out<<<dim3(BATCH * ODIM / 256), dim3(256), 0, stream>>>(bias, out);
  fkan_pipe<<<dim3(4 * 4 * KS_), dim3(256), 0, stream>>>(x, fc, out);
}

// Round 9
// 321.518 us; speedup vs baseline: 1.0023x; 1.0023x over previous
//
#include <hip/hip_runtime.h>

#define BATCH   1024
#define IDIM    256
#define ODIM    256
#define GRIDSZ  300
#define KS_     64             // K-splits over i
#define IPW     4              // i per block = IDIM/KS_
#define CHUNKS  19             // g-chunks of 16 pairs per i (last chunk: 4 pad slots)
#define NSTEPS  (IPW * CHUNKS) // 76
#define INV2PI  0.15915494309189535f

typedef __attribute__((ext_vector_type(8))) short  short8;
typedef __attribute__((ext_vector_type(4))) float  f32x4;
typedef __attribute__((ext_vector_type(4))) unsigned int u32x4;

// bf16 pair pack: round-half-up + v_perm byte select (3 VALU ops). PROVEN.
__device__ __forceinline__ unsigned pk(float c, float s) {
  unsigned a = __float_as_uint(c) + 0x8000u;
  unsigned b = __float_as_uint(s) + 0x8000u;
  return __builtin_amdgcn_perm(b, a, 0x07060302u);
}

// async global->LDS DMA, 16B per lane (lane-linear dest). [m97/m03, R5-proven]
__device__ __forceinline__ void dma16(const float* g, const float* l) {
  __builtin_amdgcn_global_load_lds(
      (const __attribute__((address_space(1))) unsigned int*)(g),
      (__attribute__((address_space(3))) unsigned int*)(l), 16, 0, 0);
}

// (c,s) *= (C,S)  — Givens rotation, 2 mul + 2 fma
__device__ __forceinline__ void rot(float& c, float& s, float C, float S) {
  float t1 = s * S, t2 = c * S;
  float cn = __builtin_fmaf(c, C, -t1);
  s = __builtin_fmaf(s, C, t2);
  c = cn;
}

// cos/sin of 2*pi*rev via v_fract + v_cos (revolutions; exact range reduction)
__device__ __forceinline__ void cossin(float rev, float& c, float& s) {
  c = __builtin_amdgcn_cosf(__builtin_amdgcn_fractf(rev));
  s = __builtin_amdgcn_cosf(__builtin_amdgcn_fractf(rev - 0.25f));
}

__global__ void init_out(const float* __restrict__ bias, float* __restrict__ out) {
  const int idx = blockIdx.x * 256 + threadIdx.x;
  out[idx] = bias[idx & (ODIM - 1)];
}

// Sum the 64 K-split partial slices + bias. 65536 threads x f32x4 each;
// lanes read consecutive 16B -> fully coalesced; 64 MB @ ~6 TB/s ~= 11 us.
__global__ __launch_bounds__(256) void reduce_ws(
    const float* __restrict__ ws, const float* __restrict__ bias,
    float* __restrict__ out) {
  const int t = blockIdx.x * 256 + threadIdx.x;   // 0..65535
  const int base = t * 4;                         // dword index into out
  f32x4 s = (f32x4){0.f, 0.f, 0.f, 0.f};
#pragma unroll 8
  for (int k = 0; k < KS_; ++k) {
    const f32x4 v = *(const f32x4*)(ws + (size_t)k * (BATCH * ODIM) + base);
    s.x += v.x; s.y += v.y; s.z += v.z; s.w += v.w;
  }
  const f32x4 bv = *(const f32x4*)(bias + (base & (ODIM - 1)));
  s.x += bv.x; s.y += bv.y; s.z += bv.z; s.w += bv.w;
  *(f32x4*)(out + base) = s;
}

// Main loop: R6 verbatim (2-deep DMA pipeline, counted vmcnt, raw barriers;
// R7's stagger/setprio removed — measured null). ONLY change: epilogue.
// TPL==1: plain stores of the block's 256x64 tile into ws slice `ks`
// (disjoint addresses, no atomics). TPL==0: R6 atomic fallback.
// R7 diagnosis: 64-way same-address atomic collisions (KS_ blocks hit each
// output element) bursting when all 1024 equal-work blocks finish together
// is the one unmeasured term in the cycle model; isolating it this round.
template <int TPL>
__global__ __launch_bounds__(256, 4) void fkan_pipe(
    const float* __restrict__ x, const float* __restrict__ fc,
    float* __restrict__ out) {
  __shared__ alignas(16) unsigned int Bp[2][1024];   // packed bf16-pair dbuf, 8 KB
  __shared__ alignas(16) float Bf[2][2048];          // fp32 DMA landing, 16 KB

  const int tid = threadIdx.x, id = blockIdx.x;
  // XCD swizzle: the 4 m-siblings of one (n,ks) are consecutive on XCD id&7.
  const int z = id & 7;
  const int m = (id >> 3) & 3;           // M/256
  const int nk = (id >> 5) * 8 + z;      // 0..255
  const int n  = nk & 3;                 // N/64
  const int ks = nk >> 2;                // 0..63

  const int wave = tid >> 6, lane = tid & 63;
  const int fr = lane & 15, fq = lane >> 4;
  const int mbase = m * 256 + wave * 64;   // 4 waves stacked along M
  const int nbase = n * 64;

  f32x4 acc[4][4];
#pragma unroll
  for (int a_ = 0; a_ < 4; ++a_)
#pragma unroll
    for (int b_ = 0; b_ < 4; ++b_)
      acc[a_][b_] = (f32x4){0.f, 0.f, 0.f, 0.f};

  float r1c[4], r1s[4], r16c[4], r16s[4], sc_[4], ss_[4];

  const float* b1 = fc + (size_t)ODIM * IDIM * GRIDSZ;   // sin-coef plane

  // staging thread's fc offset: row j = nbase+wave*16+fr, i = ks*IPW+il,
  // g = gchunk*16 + fq*4
  int fo = ((nbase + wave * 16 + fr) * IDIM + ks * IPW) * GRIDSZ + fq * 4;
  const int sa = wave * 256 + lane * 4;     // lane-linear slot (dwords)

  // prologue: DMA chunks 0 (parity 0) and 1 (parity 1)
  dma16(fc + fo, &Bf[0][sa]);
  dma16(b1 + fo, &Bf[0][1024 + sa]);
  fo += 16;                                 // chunk 1 (no wrap, no pad)
  dma16(fc + fo, &Bf[1][sa]);
  dma16(b1 + fo, &Bf[1][1024 + sa]);

  // pack chunk 0 -> Bp[0]; chunk 1's 2 DMAs stay in flight
  asm volatile("s_waitcnt vmcnt(2)" ::: "memory");
  {
    const f32x4 La = *(const f32x4*)&Bf[0][sa];
    const f32x4 Lb = *(const f32x4*)&Bf[0][1024 + sa];
    *(u32x4*)&Bp[0][sa] =
        (u32x4){pk(La.x, Lb.x), pk(La.y, Lb.y), pk(La.z, Lb.z), pk(La.w, Lb.w)};
  }

  int gs = 0, il = 0;      // compute-chunk counters (chunk S)
  int gd = 2;              // g-index of next DMA chunk (S+2)
  bool zpA = false;        // pad flag for the chunk packed this iter (S+1)

#pragma unroll 2
  for (int S = 0; S < NSTEPS; ++S) {
    __builtin_amdgcn_sched_barrier(0);
    asm volatile("s_waitcnt lgkmcnt(0)" ::: "memory");  // Bp writes committed
    __builtin_amdgcn_s_barrier();                       // NO vmcnt drain
    __builtin_amdgcn_sched_barrier(0);

    // seed A recurrence at i-boundaries (S = 0,19,38,57) BEFORE DMA issue,
    // so the compiler's wait for x doesn't drain the DMA queue.
    if (gs == 0) {
      const int i = ks * IPW + il;
#pragma unroll
      for (int tI = 0; tI < 4; ++tI) {
        const float xr = x[(size_t)(mbase + tI * 16 + fr) * IDIM + i] * INV2PI;
        cossin(xr, r1c[tI], r1s[tI]);                   // delta-k = 1
        cossin(16.0f * xr, r16c[tI], r16s[tI]);         // delta-g = 16 per chunk
        cossin((float)(fq * 4 + 1) * xr, sc_[tI], ss_[tI]);
      }
    }

    // issue DMA for chunk S+2 into Bf[S&1] (parity const under unroll-2)
    bool zpB = false;
    if (S < NSTEPS - 2) {
      if (gd == 0) fo += GRIDSZ - (CHUNKS - 1) * 16;   // row wrap: +12
      else fo += 16;
      zpB = (gd == CHUNKS - 1) & (fq == 3);            // pad quads of S+2
      const int sub = zpB ? 4 : 0;                     // shift in-bounds
      dma16(fc + fo - sub, &Bf[S & 1][sa]);
      dma16(b1 + fo - sub, &Bf[S & 1][1024 + sa]);
      gd++; if (gd == CHUNKS) gd = 0;
    }

    // B fragments for this chunk (all 4 waves read all 4 frags)
    const unsigned int* buf = &Bp[S & 1][0];
    short8 bV0 = __builtin_bit_cast(short8, *(const u32x4*)(buf + lane * 4));
    short8 bV1 = __builtin_bit_cast(short8, *(const u32x4*)(buf + 256 + lane * 4));
    short8 bV2 = __builtin_bit_cast(short8, *(const u32x4*)(buf + 512 + lane * 4));
    short8 bV3 = __builtin_bit_cast(short8, *(const u32x4*)(buf + 768 + lane * 4));

    // A frags on the fly + MFMA (pad k-slots hit zeroed B dwords)
#pragma unroll
    for (int tI = 0; tI < 4; ++tI) {
      float c = sc_[tI], s = ss_[tI];
      unsigned a0 = pk(c, s);
      rot(c, s, r1c[tI], r1s[tI]); unsigned a1 = pk(c, s);
      rot(c, s, r1c[tI], r1s[tI]); unsigned a2 = pk(c, s);
      rot(c, s, r1c[tI], r1s[tI]); unsigned a3 = pk(c, s);
      rot(sc_[tI], ss_[tI], r16c[tI], r16s[tI]);   // advance state by delta-g=16
      short8 aV = __builtin_bit_cast(short8, (u32x4){a0, a1, a2, a3});
      acc[tI][0] = __builtin_amdgcn_mfma_f32_16x16x32_bf16(aV, bV0, acc[tI][0], 0, 0, 0);
      acc[tI][1] = __builtin_amdgcn_mfma_f32_16x16x32_bf16(aV, bV1, acc[tI][1], 0, 0, 0);
      acc[tI][2] = __builtin_amdgcn_mfma_f32_16x16x32_bf16(aV, bV2, acc[tI][2], 0, 0, 0);
      acc[tI][3] = __builtin_amdgcn_mfma_f32_16x16x32_bf16(aV, bV3, acc[tI][3], 0, 0, 0);
    }

    // pack chunk S+1: counted vmcnt leaves chunk S+2's DMAs in flight
    if (S < NSTEPS - 1) {
      if (S < NSTEPS - 2) {
        asm volatile("s_waitcnt vmcnt(2)" ::: "memory");
      } else {
        asm volatile("s_waitcnt vmcnt(0)" ::: "memory");  // last chunk: drain
      }
      const f32x4 La = *(const f32x4*)&Bf[(S + 1) & 1][sa];
      const f32x4 Lb = *(const f32x4*)&Bf[(S + 1) & 1][1024 + sa];
      u32x4 w = (u32x4){pk(La.x, Lb.x), pk(La.y, Lb.y),
                        pk(La.z, Lb.z), pk(La.w, Lb.w)};
      if (zpA) w = (u32x4){0u, 0u, 0u, 0u};
      *(u32x4*)&Bp[(S + 1) & 1][sa] = w;
    }
    zpA = zpB;
    gs++; if (gs == CHUNKS) { gs = 0; ++il; }
  }

  // epilogue: C/D layout col=lane&15, row=(lane>>4)*4+reg [m89]
  const int ob = mbase + fq * 4;
  const int oj = nbase + fr;
  if (TPL) {
    // plain stores to this block's disjoint tile in ws slice `ks`
    float* wsl = out + (size_t)ks * (BATCH * ODIM);
#pragma unroll
    for (int tI = 0; tI < 4; ++tI)
#pragma unroll
      for (int tJ = 0; tJ < 4; ++tJ) {
        float* dst = wsl + (size_t)(ob + tI * 16) * ODIM + (oj + tJ * 16);
#pragma unroll
        for (int rr = 0; rr < 4; ++rr)
          dst[rr * ODIM] = acc[tI][tJ][rr];
      }
  } else {
    // atomic fallback (R6 verbatim)
#pragma unroll
    for (int tI = 0; tI < 4; ++tI)
#pragma unroll
      for (int tJ = 0; tJ < 4; ++tJ) {
        float* dst = out + (size_t)(ob + tI * 16) * ODIM + (oj + tJ * 16);
#pragma unroll
        for (int rr = 0; rr < 4; ++rr)
          unsafeAtomicAdd(dst + rr * ODIM, acc[tI][tJ][rr]);
      }
  }
}

extern "C" void kernel_launch(void* const* d_in, const int* in_sizes, int n_in,
                              void* d_out, int out_size, void* d_ws, size_t ws_size,
                              hipStream_t stream) {
  const float* x    = (const float*)d_in[0];
  const float* fc   = (const float*)d_in[1];
  const float* bias = (const float*)d_in[2];
  float* out = (float*)d_out;

  const size_t need = (size_t)KS_ * BATCH * ODIM * 4;   // 67.1 MB
  if (ws_size >= need) {
    float* ws = (float*)d_ws;
    fkan_pipe<1><<<dim3(4 * 4 * KS_), dim3(256), 0, stream>>>(x, fc, ws);
    reduce_ws<<<dim3(BATCH * ODIM / 1024), dim3(256), 0, stream>>>(ws, bias, out);
  } else {
    init_out<<<dim3(BATCH * ODIM / 256), dim3(256), 0, stream>>>(bias, out);
    fkan_pipe<0><<<dim3(4 * 4 * KS_), dim3(256), 0, stream>>>(x, fc, out);
  }
}